// Round 2
// baseline (102.718 us; speedup 1.0000x reference)
//
#include <hip/hip_runtime.h>
#include <math.h>

// HyperpriorDensity: per-channel tiny MLP CDF, evaluated at x+0.5 and x-0.5.
// out[n,c,h,w] = max(0.5*|tanh(f_c(x+0.5)/2) - tanh(f_c(x-0.5)/2)|, 1e-9)
// (identity: |sigmoid(a)-sigmoid(b)| = 0.5|tanh(a/2)-tanh(b/2)| — replaces the
//  reference's sign/stop_gradient stabilization exactly, no cancellation.)

constexpr int HW = 1024;       // 32*32 spatial elements per (n,c) slab
constexpr float MINL = 1e-9f;

__device__ __forceinline__ float softplus_f(float v) {
    // numerically robust softplus
    return fmaxf(v, 0.0f) + log1pf(expf(-fabsf(v)));
}

// q layout (registers, all constant-indexed):
//  [0..2]   sp(H0)   [3..11]  sp(H1)  [12..20] sp(H2)  [21..23] sp(H3)
//  [24..26] th(a0)   [27..29] th(a1)  [30..32] th(a2)  [33]     th(a3)
//  [34..36] b0       [37..39] b1      [40..42] b2      [43]     b3
template<bool GATED>
__device__ __forceinline__ float cdf_t(float u, const float* q) {
    float y0 = fmaf(q[0], u, q[34]);
    float y1 = fmaf(q[1], u, q[35]);
    float y2 = fmaf(q[2], u, q[36]);
    if (GATED) {
        y0 = fmaf(q[24], tanhf(y0), y0);
        y1 = fmaf(q[25], tanhf(y1), y1);
        y2 = fmaf(q[26], tanhf(y2), y2);
    }
    float z0 = fmaf(q[3], y0, fmaf(q[4],  y1, fmaf(q[5],  y2, q[37])));
    float z1 = fmaf(q[6], y0, fmaf(q[7],  y1, fmaf(q[8],  y2, q[38])));
    float z2 = fmaf(q[9], y0, fmaf(q[10], y1, fmaf(q[11], y2, q[39])));
    if (GATED) {
        z0 = fmaf(q[27], tanhf(z0), z0);
        z1 = fmaf(q[28], tanhf(z1), z1);
        z2 = fmaf(q[29], tanhf(z2), z2);
    }
    float w0 = fmaf(q[12], z0, fmaf(q[13], z1, fmaf(q[14], z2, q[40])));
    float w1 = fmaf(q[15], z0, fmaf(q[16], z1, fmaf(q[17], z2, q[41])));
    float w2 = fmaf(q[18], z0, fmaf(q[19], z1, fmaf(q[20], z2, q[42])));
    if (GATED) {
        w0 = fmaf(q[30], tanhf(w0), w0);
        w1 = fmaf(q[31], tanhf(w1), w1);
        w2 = fmaf(q[32], tanhf(w2), w2);
    }
    float s = fmaf(q[21], w0, fmaf(q[22], w1, fmaf(q[23], w2, q[43])));
    if (GATED) s = fmaf(q[33], tanhf(s), s);
    return tanhf(0.5f * s);
}

template<bool GATED>
__device__ __forceinline__ float elem_like(float v, const float* q) {
    float tu = cdf_t<GATED>(v + 0.5f, q);
    float tl = cdf_t<GATED>(v - 0.5f, q);
    return fmaxf(0.5f * fabsf(tu - tl), MINL);
}

__global__ __launch_bounds__(256)
void hyperprior_density_kernel(
    const float* __restrict__ x,
    const float* __restrict__ H0, const float* __restrict__ a0, const float* __restrict__ b0,
    const float* __restrict__ H1, const float* __restrict__ a1, const float* __restrict__ b1,
    const float* __restrict__ H2, const float* __restrict__ a2, const float* __restrict__ b2,
    const float* __restrict__ H3, const float* __restrict__ a3, const float* __restrict__ b3,
    float* __restrict__ out, int C)
{
    __shared__ float p[44];
    const int c   = blockIdx.x;      // channel
    const int n   = blockIdx.y;      // batch slab
    const int tid = threadIdx.x;

    // ---- stage per-channel params into LDS (one thread per param) ----
    if (tid < 24) {
        float h;
        if      (tid < 3)  h = H0[c * 3 + tid];
        else if (tid < 12) h = H1[c * 9 + (tid - 3)];
        else if (tid < 21) h = H2[c * 9 + (tid - 12)];
        else               h = H3[c * 3 + (tid - 21)];
        p[tid] = softplus_f(h);
    } else if (tid < 34) {
        int i = tid - 24;
        float av;
        if      (i < 3) av = a0[c * 3 + i];
        else if (i < 6) av = a1[c * 3 + (i - 3)];
        else if (i < 9) av = a2[c * 3 + (i - 6)];
        else            av = a3[c];
        p[tid] = tanhf(av);
    } else if (tid < 44) {
        int i = tid - 34;
        float bv;
        if      (i < 3) bv = b0[c * 3 + i];
        else if (i < 6) bv = b1[c * 3 + (i - 3)];
        else if (i < 9) bv = b2[c * 3 + (i - 6)];
        else            bv = b3[c];
        p[tid] = bv;
    }
    __syncthreads();

    // copy params LDS -> registers (constant indices => stays in VGPRs)
    float q[44];
#pragma unroll
    for (int i = 0; i < 44; ++i) q[i] = p[i];

    // uniform per-block gate check: a==0 => tanh(a)==0 => gating terms vanish
    bool gated = false;
#pragma unroll
    for (int i = 24; i < 34; ++i) gated = gated || (q[i] != 0.0f);

    const size_t base = ((size_t)n * (size_t)C + (size_t)c) * (size_t)HW;
    const float4* xin = reinterpret_cast<const float4*>(x + base);
    float4*       op  = reinterpret_cast<float4*>(out + base);

    float4 v = xin[tid];
    float4 r;
    if (!gated) {
        r.x = elem_like<false>(v.x, q);
        r.y = elem_like<false>(v.y, q);
        r.z = elem_like<false>(v.z, q);
        r.w = elem_like<false>(v.w, q);
    } else {
        r.x = elem_like<true>(v.x, q);
        r.y = elem_like<true>(v.y, q);
        r.z = elem_like<true>(v.z, q);
        r.w = elem_like<true>(v.w, q);
    }
    op[tid] = r;
}

extern "C" void kernel_launch(void* const* d_in, const int* in_sizes, int n_in,
                              void* d_out, int out_size, void* d_ws, size_t ws_size,
                              hipStream_t stream) {
    const float* x  = (const float*)d_in[0];
    const float* H0 = (const float*)d_in[1];
    const float* a0 = (const float*)d_in[2];
    const float* b0 = (const float*)d_in[3];
    const float* H1 = (const float*)d_in[4];
    const float* a1 = (const float*)d_in[5];
    const float* b1 = (const float*)d_in[6];
    const float* H2 = (const float*)d_in[7];
    const float* a2 = (const float*)d_in[8];
    const float* b2 = (const float*)d_in[9];
    const float* H3 = (const float*)d_in[10];
    const float* a3 = (const float*)d_in[11];
    const float* b3 = (const float*)d_in[12];
    float* out = (float*)d_out;

    const int C = in_sizes[1] / 3;            // H0 is (C,3,1)
    const int N = in_sizes[0] / (C * HW);     // x is (N,C,32,32)

    dim3 grid(C, N);
    hipLaunchKernelGGL(hyperprior_density_kernel, grid, dim3(256), 0, stream,
                       x, H0, a0, b0, H1, a1, b1, H2, a2, b2, H3, a3, b3, out, C);
}